// Round 1
// baseline (130.877 us; speedup 1.0000x reference)
//
#include <hip/hip_runtime.h>
#include <stdint.h>

#define WW 128
#define KK 32
#define NC 9
#define NCELL (WW * KK)

__device__ __forceinline__ float wrapf(float x) {
  const float kPi = 3.14159265358979323846f;
  const float kTwoPi = 6.28318530717958647692f;
  float y = fmodf(x + kPi, kTwoPi);   // lax.rem semantics (sign of dividend)
  y = (y < 0.0f) ? (y + kTwoPi) : y;  // jnp.mod fixup for positive divisor
  return y - kPi;
}

__device__ __forceinline__ uint32_t ordf(float f) {
  uint32_t u = __float_as_uint(f);
  return (u & 0x80000000u) ? ~u : (u | 0x80000000u);
}

__global__ __launch_bounds__(256) void linker_kernel(
    const float* __restrict__ tokens, float* __restrict__ out,
    int* __restrict__ counts) {
  const int b = blockIdx.x;
  const int tid = threadIdx.x;
  const float* T = tokens + (size_t)b * NCELL * NC;

  __shared__ int8_t s_pred[NCELL];
  __shared__ int8_t s_member[NCELL];
  __shared__ int8_t s_succ[NCELL];
  __shared__ int8_t s_predcol[NCELL];
  __shared__ int8_t s_chaincol[KK * WW];
  __shared__ float s_chainsum[KK];
  __shared__ int s_chainlen[KK];
  __shared__ unsigned long long s_win[KK];
  __shared__ int s_count;

  for (int i = tid; i < NCELL; i += 256) {
    s_member[i] = -1;
    s_succ[i] = -1;
    s_predcol[i] = -1;
  }
  if (tid < KK) s_win[tid] = 0ull;
  __syncthreads();

  // ---------------- DP over windows (wave 0, lanes = columns) --------------
  if (tid < KK) {
    const int k = tid;
    float snr0 = T[k * NC + 0];
    bool v0 = snr0 > 0.0f;
    float prev_best = v0 ? snr0 : -INFINITY;
    int prev_root = k;
    float prev_fe = T[k * NC + 4];
    float prev_Ae = T[k * NC + 6];
    float prev_pe = T[k * NC + 8];
    s_pred[k] = -1;
    if (v0) {
      unsigned long long key =
          ((unsigned long long)ordf(snr0) << 32) | (uint32_t)(~(uint32_t)k);
      atomicMax(&s_win[k], key);
    }
    for (int w = 1; w < WW; ++w) {
      const float* Cw = T + (size_t)(w * KK + k) * NC;
      float snr_c = Cw[0];
      float fs = Cw[3], As = Cw[5], ps = Cw[7];
      float fe_r = Cw[4], Ae_r = Cw[6], pe_r = Cw[8];
      bool scur = snr_c > 0.0f;
      float bestE = -INFINITY;
      int arg = 0;
      // wave-uniform mask of predecessors with finite best (implies snr>0)
      unsigned int m = (unsigned int)__ballot(prev_best > -INFINITY);
      while (m) {
        int kp = __ffs(m) - 1;
        m &= m - 1;
        float bp = __shfl(prev_best, kp);
        float fe = __shfl(prev_fe, kp);
        float ae = __shfl(prev_Ae, kp);
        float pe = __shfl(prev_pe, kp);
        float fm = (fe + fs) * 0.5f;
        float fden = (fm > 0.0f) ? fm : 1.0f;
        bool fbad = (fm > 0.0f) && (fabsf(fe - fs) / fden > 0.05f);
        float am = fmaxf(ae, As);
        float aden = (am > 0.0f) ? am : 1.0f;
        bool abad = (am > 0.0f) && (fabsf(ae - As) / aden > 0.5f);
        bool pok = fabsf(wrapf(ps - pe)) <= 0.5f;
        if (scur && !fbad && !abad && pok) {
          float cand = bp + snr_c;
          if (cand > bestE) { bestE = cand; arg = kp; }  // first-max, asc kp
        }
      }
      bool has = bestE > -INFINITY;
      s_pred[w * KK + k] = (int8_t)(has ? arg : -1);
      int rsrc = has ? arg : 0;
      int rootc = __shfl(prev_root, rsrc);
      int root_new = has ? rootc : k;
      float bnew = has ? bestE : -INFINITY;
      if (has) {
        int idx = w * KK + k;
        unsigned long long key = ((unsigned long long)ordf(bnew) << 32) |
                                 (uint32_t)(~(uint32_t)idx);
        atomicMax(&s_win[root_new], key);
      }
      prev_best = bnew;
      prev_root = root_new;
      prev_fe = fe_r;
      prev_Ae = Ae_r;
      prev_pe = pe_r;
    }
  }
  __syncthreads();

  // ------------- winner ranking + chain commit (lanes 0..31) ---------------
  if (tid < KK) {
    unsigned long long wk = s_win[tid];
    bool exists = (wk != 0ull);
    int idx = exists ? (int)(~(uint32_t)(wk & 0xFFFFFFFFull)) : -1;
    int we = idx >> 5;  // -1 stays -1
    int ke = idx & 31;
    bool enr = exists && (we >= 1);
    int cid = 0;
    for (int r2 = 0; r2 < KK; ++r2) {
      unsigned long long k2 = __shfl(wk, r2);
      int e2 = __shfl((int)enr, r2);
      if (e2 && k2 > wk) cid++;
    }
    unsigned long long bal = __ballot(enr);
    int total = __popcll(bal);
    if (tid == 0) { s_count = total; counts[b] = total; }
    if (enr) {
      s_chainlen[cid] = we + 1;
      int cw = we, ck = ke, prevc = -1;
      while (cw >= 0) {
        int cell = (cw << 5) | ck;
        s_member[cell] = (int8_t)cid;
        s_succ[cell] = (int8_t)prevc;
        if (prevc >= 0) s_predcol[((cw + 1) << 5) | prevc] = (int8_t)ck;
        s_chaincol[cid * WW + cw] = (int8_t)ck;
        prevc = ck;
        ck = s_pred[cell];
        cw--;
      }
    }
  }
  __syncthreads();

  // --------- per-chain snr^2 sums (window-ascending, matches segsum) -------
  if (tid < KK && tid < s_count) {
    int len = s_chainlen[tid];
    float sum = 0.0f;
    for (int w = 0; w < len; ++w) {
      int col = s_chaincol[tid * WW + w];
      float s = T[(size_t)(w * KK + col) * NC + 0];
      sum += s * s;
    }
    s_chainsum[tid] = sum;
  }
  __syncthreads();

  // ------------------------------- output ----------------------------------
  for (int i = tid; i < NCELL; i += 256) {
    int w = i >> 5;
    const float* C = T + (size_t)i * NC;
    float t0 = C[0], t1 = C[1], t2 = C[2], t3 = C[3], t4 = C[4], t5 = C[5],
          t6 = C[6], t7 = C[7], t8 = C[8];
    int mm = s_member[i];
    int sc = s_succ[i];
    int pc = s_predcol[i];
    float o0 = (mm >= 0) ? sqrtf(s_chainsum[mm]) : t0;
    float o3 = t3, o5 = t5, o7 = t7;
    if (pc >= 0) {  // predecessor at (w-1, pc) rewrites my start-side fields
      const float* P = T + (size_t)((w - 1) * KK + pc) * NC;
      float fep = P[4], aep = P[6], pep = P[8];
      o3 = (fep + t3) * 0.5f;
      o5 = (aep + t5) * 0.5f;
      float corr = wrapf(t7 - pep);
      o7 = t7 - corr * 0.5f;
    }
    float o4 = t4, o6 = t6, o8 = t8;
    if (sc >= 0) {  // successor at (w+1, sc) rewrites my end-side fields
      const float* S = T + (size_t)((w + 1) * KK + sc) * NC;
      float fsn = S[3], asn = S[5], psn = S[7];
      o4 = (t4 + fsn) * 0.5f;
      o6 = (t6 + asn) * 0.5f;
      float corr = wrapf(psn - t8);
      o8 = t8 + corr * 0.5f;
    }
    float* O = out + ((size_t)b * NCELL + i) * 10;
    O[0] = o0; O[1] = t1; O[2] = t2; O[3] = o3; O[4] = o4;
    O[5] = o5; O[6] = o6; O[7] = o7; O[8] = o8;
    O[9] = (float)mm;  // local member id; global offset added in pass 2
  }
}

__global__ void cid_kernel(const int* __restrict__ counts,
                           float* __restrict__ out, int B) {
  __shared__ int offs[256];
  if (threadIdx.x == 0) {
    int acc = 0;
    for (int i = 0; i < B; ++i) { offs[i] = acc; acc += counts[i]; }
  }
  __syncthreads();
  int total = B * NCELL;
  for (int i = threadIdx.x; i < total; i += blockDim.x) {
    int bb = i >> 12;  // NCELL = 4096
    size_t p = (size_t)i * 10 + 9;
    float v = out[p];
    if (v >= 0.0f) out[p] = v + (float)offs[bb];
  }
}

extern "C" void kernel_launch(void* const* d_in, const int* in_sizes, int n_in,
                              void* d_out, int out_size, void* d_ws,
                              size_t ws_size, hipStream_t stream) {
  const float* tokens = (const float*)d_in[0];
  float* out = (float*)d_out;
  int B = in_sizes[0] / (WW * KK * NC);
  int* counts = (int*)d_ws;
  linker_kernel<<<dim3(B), dim3(256), 0, stream>>>(tokens, out, counts);
  cid_kernel<<<dim3(1), dim3(256), 0, stream>>>(counts, out, B);
}

// Round 2
// 56.791 us; speedup vs baseline: 2.3046x; 2.3046x over previous
//
#include <hip/hip_runtime.h>
#include <stdint.h>

#define WW 128
#define KK 32
#define NC 9
#define NCELL (WW * KK)

__device__ __forceinline__ float wrapf(float x) {
  const float kPi = 3.14159265358979323846f;
  const float kTwoPi = 6.28318530717958647692f;
  float y = fmodf(x + kPi, kTwoPi);   // lax.rem semantics (sign of dividend)
  y = (y < 0.0f) ? (y + kTwoPi) : y;  // jnp.mod fixup for positive divisor
  return y - kPi;
}

__device__ __forceinline__ uint32_t ordf(float f) {
  uint32_t u = __float_as_uint(f);
  return (u & 0x80000000u) ? ~u : (u | 0x80000000u);
}

struct Row {
  float snr, fs, fe, As, Ae, ps, pe;
};

__device__ __forceinline__ Row loadRow(const float* __restrict__ T, int w,
                                       int k) {
  const float* C = T + (size_t)(w * KK + k) * NC;
  Row r;
  r.snr = C[0];
  r.fs = C[3];
  r.fe = C[4];
  r.As = C[5];
  r.Ae = C[6];
  r.ps = C[7];
  r.pe = C[8];
  return r;
}

__global__ __launch_bounds__(256) void linker_kernel(
    const float* __restrict__ tokens, float* __restrict__ out,
    int* __restrict__ counts) {
  const int b = blockIdx.x;
  const int tid = threadIdx.x;
  const float* T = tokens + (size_t)b * NCELL * NC;

  __shared__ int8_t s_pred[NCELL];
  __shared__ int8_t s_member[NCELL];
  __shared__ int8_t s_succ[NCELL];
  __shared__ int8_t s_predcol[NCELL];
  __shared__ int8_t s_chaincol[KK * WW];
  __shared__ float s_chainsum[KK];
  __shared__ int s_chainlen[KK];
  __shared__ unsigned long long s_win[KK];
  __shared__ int s_count;

  for (int i = tid; i < NCELL; i += 256) {
    s_member[i] = -1;
    s_succ[i] = -1;
    s_predcol[i] = -1;
  }
  if (tid < KK) s_win[tid] = 0ull;
  __syncthreads();

  // ---------------- DP over windows (wave 0, 64 lanes) ---------------------
  // Lanes (k, h): k = column 0..31, h = half 0/1. Both halves carry
  // replicated DP state; the inner pred-scan pops 2 set bits per uniform
  // iteration (h=0 first bit, h=1 second bit).
  if (tid < 64) {
    const int k = tid & 31;
    const int h = tid >> 5;
    float snr0 = T[k * NC + 0];
    bool v0 = snr0 > 0.0f;
    float prev_best = v0 ? snr0 : -INFINITY;
    int prev_root = k;
    float prev_fe = T[k * NC + 4];
    float prev_Ae = T[k * NC + 6];
    float prev_pe = T[k * NC + 8];
    if (h == 0) {
      s_pred[k] = -1;
      if (v0) {
        unsigned long long key =
            ((unsigned long long)ordf(snr0) << 32) | (uint32_t)(~(uint32_t)k);
        atomicMax(&s_win[k], key);
      }
    }
    // depth-2 register prefetch of the current column's rows
    Row cur = loadRow(T, 1, k);
    Row nxt = loadRow(T, (2 < WW) ? 2 : (WW - 1), k);
    for (int w = 1; w < WW; ++w) {
      int wf = (w + 2 < WW) ? (w + 2) : (WW - 1);
      Row fut = loadRow(T, wf, k);  // independent of DP carry -> overlaps

      bool scur = cur.snr > 0.0f;
      float bestE = -INFINITY;
      int arg = 0;
      unsigned long long full = __ballot(prev_best > -INFINITY);
      unsigned int rem = (unsigned int)full;  // uniform across wave
      while (rem) {  // uniform trip count: 2 bits per iteration
        int kp0 = __ffs(rem) - 1;
        rem &= rem - 1;
        bool have2 = rem != 0u;
        int kp1 = have2 ? (__ffs(rem) - 1) : kp0;
        if (have2) rem &= rem - 1;
        int kp = h ? kp1 : kp0;
        bool lane_ok = h ? have2 : true;
        float bp = __shfl(prev_best, kp);
        float fe = __shfl(prev_fe, kp);
        float ae = __shfl(prev_Ae, kp);
        float pe = __shfl(prev_pe, kp);
        float fm = (fe + cur.fs) * 0.5f;
        float fden = (fm > 0.0f) ? fm : 1.0f;
        bool fbad = (fm > 0.0f) && (fabsf(fe - cur.fs) / fden > 0.05f);
        float am = fmaxf(ae, cur.As);
        float aden = (am > 0.0f) ? am : 1.0f;
        bool abad = (am > 0.0f) && (fabsf(ae - cur.As) / aden > 0.5f);
        bool pok = fabsf(wrapf(cur.ps - pe)) <= 0.5f;
        if (lane_ok && scur && !fbad && !abad && pok) {
          float cand = bp + cur.snr;
          if (cand > bestE) { bestE = cand; arg = kp; }  // first-max in half
        }
      }
      // combine halves; exact jnp argmax tie-break = smallest kp among maxima
      float ob = __shfl_xor(bestE, 32);
      int oa = __shfl_xor(arg, 32);
      float b0 = h ? ob : bestE;
      float b1 = h ? bestE : ob;
      int a0 = h ? oa : arg;
      int a1 = h ? arg : oa;
      bool take0 = (b0 > b1) || ((b0 == b1) && (a0 <= a1));
      float bE = take0 ? b0 : b1;
      int aC = take0 ? a0 : a1;
      bool has = bE > -INFINITY;
      if (h == 0) s_pred[w * KK + k] = (int8_t)(has ? aC : -1);
      int rsrc = has ? aC : 0;
      int rootc = __shfl(prev_root, rsrc);
      int root_new = has ? rootc : k;
      float bnew = has ? bE : -INFINITY;
      if (has && h == 0) {
        int idx = w * KK + k;
        unsigned long long key = ((unsigned long long)ordf(bnew) << 32) |
                                 (uint32_t)(~(uint32_t)idx);
        atomicMax(&s_win[root_new], key);
      }
      prev_best = bnew;
      prev_root = root_new;
      prev_fe = cur.fe;
      prev_Ae = cur.Ae;
      prev_pe = cur.pe;
      cur = nxt;
      nxt = fut;
    }
  }
  __syncthreads();

  // ------------- winner ranking + chain commit (lanes 0..31) ---------------
  if (tid < KK) {
    unsigned long long wk = s_win[tid];
    bool exists = (wk != 0ull);
    int idx = exists ? (int)(~(uint32_t)(wk & 0xFFFFFFFFull)) : -1;
    int we = idx >> 5;  // -1 stays -1
    int ke = idx & 31;
    bool enr = exists && (we >= 1);
    int cid = 0;
    for (int r2 = 0; r2 < KK; ++r2) {
      unsigned long long k2 = __shfl(wk, r2);
      int e2 = __shfl((int)enr, r2);
      if (e2 && k2 > wk) cid++;
    }
    unsigned long long bal = __ballot(enr);
    int total = __popcll(bal);
    if (tid == 0) { s_count = total; counts[b] = total; }
    if (enr) {
      s_chainlen[cid] = we + 1;
      int cw = we, ck = ke, prevc = -1;
      while (cw >= 0) {
        int cell = (cw << 5) | ck;
        s_member[cell] = (int8_t)cid;
        s_succ[cell] = (int8_t)prevc;
        if (prevc >= 0) s_predcol[((cw + 1) << 5) | prevc] = (int8_t)ck;
        s_chaincol[cid * WW + cw] = (int8_t)ck;
        prevc = ck;
        ck = s_pred[cell];
        cw--;
      }
    }
  }
  __syncthreads();

  // --------- per-chain snr^2 sums (window-ascending, matches segsum) -------
  if (tid < KK && tid < s_count) {
    int len = s_chainlen[tid];
    float sum = 0.0f;
    for (int w = 0; w < len; ++w) {
      int col = s_chaincol[tid * WW + w];
      float s = T[(size_t)(w * KK + col) * NC + 0];
      sum += s * s;
    }
    s_chainsum[tid] = sum;
  }
  __syncthreads();

  // ------------------------------- output ----------------------------------
  for (int i = tid; i < NCELL; i += 256) {
    int w = i >> 5;
    const float* C = T + (size_t)i * NC;
    float t0 = C[0], t1 = C[1], t2 = C[2], t3 = C[3], t4 = C[4], t5 = C[5],
          t6 = C[6], t7 = C[7], t8 = C[8];
    int mm = s_member[i];
    int sc = s_succ[i];
    int pc = s_predcol[i];
    float o0 = (mm >= 0) ? sqrtf(s_chainsum[mm]) : t0;
    float o3 = t3, o5 = t5, o7 = t7;
    if (pc >= 0) {  // predecessor at (w-1, pc) rewrites my start-side fields
      const float* P = T + (size_t)((w - 1) * KK + pc) * NC;
      float fep = P[4], aep = P[6], pep = P[8];
      o3 = (fep + t3) * 0.5f;
      o5 = (aep + t5) * 0.5f;
      float corr = wrapf(t7 - pep);
      o7 = t7 - corr * 0.5f;
    }
    float o4 = t4, o6 = t6, o8 = t8;
    if (sc >= 0) {  // successor at (w+1, sc) rewrites my end-side fields
      const float* S = T + (size_t)((w + 1) * KK + sc) * NC;
      float fsn = S[3], asn = S[5], psn = S[7];
      o4 = (t4 + fsn) * 0.5f;
      o6 = (t6 + asn) * 0.5f;
      float corr = wrapf(psn - t8);
      o8 = t8 + corr * 0.5f;
    }
    float* O = out + ((size_t)b * NCELL + i) * 10;
    O[0] = o0; O[1] = t1; O[2] = t2; O[3] = o3; O[4] = o4;
    O[5] = o5; O[6] = o6; O[7] = o7; O[8] = o8;
    O[9] = (float)mm;  // local member id; global offset added in pass 2
  }
}

#define CID_SLICES 8

__global__ __launch_bounds__(256) void cid_kernel(
    const int* __restrict__ counts, float* __restrict__ out) {
  const int bb = blockIdx.x / CID_SLICES;
  const int sl = blockIdx.x % CID_SLICES;
  int off = 0;
  for (int i = 0; i < bb; ++i) off += counts[i];
  if (off == 0) return;  // nothing to add for this batch
  const int slice = NCELL / CID_SLICES;  // 512
  const int base = bb * NCELL + sl * slice;
  for (int j = threadIdx.x; j < slice; j += 256) {
    size_t p = (size_t)(base + j) * 10 + 9;
    float v = out[p];
    if (v >= 0.0f) out[p] = v + (float)off;
  }
}

extern "C" void kernel_launch(void* const* d_in, const int* in_sizes, int n_in,
                              void* d_out, int out_size, void* d_ws,
                              size_t ws_size, hipStream_t stream) {
  const float* tokens = (const float*)d_in[0];
  float* out = (float*)d_out;
  int B = in_sizes[0] / (WW * KK * NC);
  int* counts = (int*)d_ws;
  linker_kernel<<<dim3(B), dim3(256), 0, stream>>>(tokens, out, counts);
  cid_kernel<<<dim3(B * CID_SLICES), dim3(256), 0, stream>>>(counts, out);
}

// Round 3
// 28.216 us; speedup vs baseline: 4.6385x; 2.0127x over previous
//
#include <hip/hip_runtime.h>
#include <stdint.h>

#define WW 128
#define KK 32
#define NC 9
#define NCELL (WW * KK)
#define OSLICES 16  // out_kernel blocks per batch (256 cells each)

__device__ __forceinline__ float wrapf(float x) {
  const float kPi = 3.14159265358979323846f;
  const float kTwoPi = 6.28318530717958647692f;
  float y = fmodf(x + kPi, kTwoPi);   // lax.rem semantics (sign of dividend)
  y = (y < 0.0f) ? (y + kTwoPi) : y;  // jnp.mod fixup for positive divisor
  return y - kPi;
}

__device__ __forceinline__ uint32_t ordf(float f) {
  uint32_t u = __float_as_uint(f);
  return (u & 0x80000000u) ? ~u : (u | 0x80000000u);
}

struct Row {
  float snr, fs, fe, As, Ae, ps, pe;
};

__device__ __forceinline__ Row loadRow(const float* __restrict__ T, int w,
                                       int k) {
  const float* C = T + (size_t)(w * KK + k) * NC;
  Row r;
  r.snr = C[0];
  r.fs = C[3];
  r.fe = C[4];
  r.As = C[5];
  r.Ae = C[6];
  r.ps = C[7];
  r.pe = C[8];
  return r;
}

// ---------------------------------------------------------------------------
// Kernel 1: per-batch DP + winner selection + chain commit.
// Publishes: counts[b], chainsums[b*KK+c], and per-cell packed
// {member,succ,predcol} (3 x int8) in the bit pattern of out[cell*10+9]
// (out_kernel reads the bits, then overwrites the float).
// ---------------------------------------------------------------------------
__global__ __launch_bounds__(256) void dp_kernel(
    const float* __restrict__ tokens, float* __restrict__ out,
    int* __restrict__ counts, float* __restrict__ chainsums) {
  const int b = blockIdx.x;
  const int tid = threadIdx.x;
  const float* T = tokens + (size_t)b * NCELL * NC;

  __shared__ int8_t s_pred[NCELL];
  __shared__ int8_t s_member[NCELL];
  __shared__ int8_t s_succ[NCELL];
  __shared__ int8_t s_predcol[NCELL];
  __shared__ int8_t s_chaincol[KK * WW];
  __shared__ int s_chainlen[KK];
  __shared__ unsigned long long s_win[KK];
  __shared__ int s_count;

  for (int i = tid; i < NCELL; i += 256) {
    s_member[i] = -1;
    s_succ[i] = -1;
    s_predcol[i] = -1;
  }
  if (tid < KK) s_win[tid] = 0ull;
  __syncthreads();

  // ---------------- DP over windows (wave 0, 64 lanes) ---------------------
  // Lanes (k, h): k = column 0..31, h = half 0/1; replicated DP state, the
  // inner pred-scan pops 2 set bits per uniform iteration.
  // Early exit: once no column is reachable (ballot==0), no later s_pred
  // entry is ever read and no s_win update can fire -> break.
  if (tid < 64) {
    const int k = tid & 31;
    const int h = tid >> 5;
    float snr0 = T[k * NC + 0];
    bool v0 = snr0 > 0.0f;
    float prev_best = v0 ? snr0 : -INFINITY;
    int prev_root = k;
    float prev_fe = T[k * NC + 4];
    float prev_Ae = T[k * NC + 6];
    float prev_pe = T[k * NC + 8];
    if (h == 0) {
      s_pred[k] = -1;
      if (v0) {
        unsigned long long key =
            ((unsigned long long)ordf(snr0) << 32) | (uint32_t)(~(uint32_t)k);
        atomicMax(&s_win[k], key);
      }
    }
    Row cur = loadRow(T, 1, k);
    Row nxt = loadRow(T, 2, k);
    for (int w = 1; w < WW; ++w) {
      unsigned long long full = __ballot(prev_best > -INFINITY);
      if (full == 0ull) break;  // reachable set extinct: nothing left to do

      int wf = (w + 2 < WW) ? (w + 2) : (WW - 1);
      Row fut = loadRow(T, wf, k);  // independent of DP carry -> overlaps

      bool scur = cur.snr > 0.0f;
      float bestE = -INFINITY;
      int arg = 0;
      unsigned int rem = (unsigned int)full;  // uniform across wave
      while (rem) {  // uniform trip count: 2 bits per iteration
        int kp0 = __ffs(rem) - 1;
        rem &= rem - 1;
        bool have2 = rem != 0u;
        int kp1 = have2 ? (__ffs(rem) - 1) : kp0;
        if (have2) rem &= rem - 1;
        int kp = h ? kp1 : kp0;
        bool lane_ok = h ? have2 : true;
        float bp = __shfl(prev_best, kp);
        float fe = __shfl(prev_fe, kp);
        float ae = __shfl(prev_Ae, kp);
        float pe = __shfl(prev_pe, kp);
        float fm = (fe + cur.fs) * 0.5f;
        float fden = (fm > 0.0f) ? fm : 1.0f;
        bool fbad = (fm > 0.0f) && (fabsf(fe - cur.fs) / fden > 0.05f);
        float am = fmaxf(ae, cur.As);
        float aden = (am > 0.0f) ? am : 1.0f;
        bool abad = (am > 0.0f) && (fabsf(ae - cur.As) / aden > 0.5f);
        bool pok = fabsf(wrapf(cur.ps - pe)) <= 0.5f;
        if (lane_ok && scur && !fbad && !abad && pok) {
          float cand = bp + cur.snr;
          if (cand > bestE) { bestE = cand; arg = kp; }  // first-max in half
        }
      }
      // combine halves; exact jnp argmax tie-break = smallest kp among maxima
      float ob = __shfl_xor(bestE, 32);
      int oa = __shfl_xor(arg, 32);
      float b0 = h ? ob : bestE;
      float b1 = h ? bestE : ob;
      int a0 = h ? oa : arg;
      int a1 = h ? arg : oa;
      bool take0 = (b0 > b1) || ((b0 == b1) && (a0 <= a1));
      float bE = take0 ? b0 : b1;
      int aC = take0 ? a0 : a1;
      bool has = bE > -INFINITY;
      if (h == 0) s_pred[w * KK + k] = (int8_t)(has ? aC : -1);
      int rsrc = has ? aC : 0;
      int rootc = __shfl(prev_root, rsrc);
      int root_new = has ? rootc : k;
      float bnew = has ? bE : -INFINITY;
      if (has && h == 0) {
        int idx = w * KK + k;
        unsigned long long key = ((unsigned long long)ordf(bnew) << 32) |
                                 (uint32_t)(~(uint32_t)idx);
        atomicMax(&s_win[root_new], key);
      }
      prev_best = bnew;
      prev_root = root_new;
      prev_fe = cur.fe;
      prev_Ae = cur.Ae;
      prev_pe = cur.pe;
      cur = nxt;
      nxt = fut;
    }
  }
  __syncthreads();

  // ------------- winner ranking + chain commit (lanes 0..31) ---------------
  if (tid < KK) {
    unsigned long long wk = s_win[tid];
    bool exists = (wk != 0ull);
    int idx = exists ? (int)(~(uint32_t)(wk & 0xFFFFFFFFull)) : -1;
    int we = idx >> 5;  // -1 stays -1
    int ke = idx & 31;
    bool enr = exists && (we >= 1);
    int cid = 0;
    for (int r2 = 0; r2 < KK; ++r2) {
      unsigned long long k2 = __shfl(wk, r2);
      int e2 = __shfl((int)enr, r2);
      if (e2 && k2 > wk) cid++;
    }
    unsigned long long bal = __ballot(enr);
    int total = __popcll(bal);
    if (tid == 0) { s_count = total; counts[b] = total; }
    if (enr) {
      s_chainlen[cid] = we + 1;
      int cw = we, ck = ke, prevc = -1;
      while (cw >= 0) {
        int cell = (cw << 5) | ck;
        s_member[cell] = (int8_t)cid;
        s_succ[cell] = (int8_t)prevc;
        if (prevc >= 0) s_predcol[((cw + 1) << 5) | prevc] = (int8_t)ck;
        s_chaincol[cid * WW + cw] = (int8_t)ck;
        prevc = ck;
        ck = s_pred[cell];
        cw--;
      }
    }
  }
  __syncthreads();

  // --------- per-chain snr^2 sums (window-ascending, matches segsum) -------
  if (tid < KK && tid < s_count) {
    int len = s_chainlen[tid];
    float sum = 0.0f;
    for (int w = 0; w < len; ++w) {
      int col = s_chaincol[tid * WW + w];
      float s = T[(size_t)(w * KK + col) * NC + 0];
      sum += s * s;
    }
    chainsums[b * KK + tid] = sum;
  }
  __syncthreads();

  // ---- publish packed per-cell {member, succ, predcol} into out[...,9] ----
  int* outi = (int*)out;
  for (int i = tid; i < NCELL; i += 256) {
    int mm = s_member[i];
    int sc = s_succ[i];
    int pc = s_predcol[i];
    int packed = (mm & 0xFF) | ((sc & 0xFF) << 8) | ((pc & 0xFF) << 16);
    outi[((size_t)b * NCELL + i) * 10 + 9] = packed;
  }
}

// ---------------------------------------------------------------------------
// Kernel 2: fully parallel output formatting, 1 cell/thread, B*OSLICES blocks.
// Reads packed cell info from out[...,9] bits, writes final 10 floats
// including globally-offset chain id.
// ---------------------------------------------------------------------------
__global__ __launch_bounds__(256) void out_kernel(
    const float* __restrict__ tokens, float* __restrict__ out,
    const int* __restrict__ counts, const float* __restrict__ chainsums,
    int B) {
  const int bb = blockIdx.x >> 4;  // OSLICES == 16
  const int sl = blockIdx.x & 15;
  __shared__ int s_counts[64];
  if (threadIdx.x < B) s_counts[threadIdx.x] = counts[threadIdx.x];
  __syncthreads();
  int off = 0;
  for (int j = 0; j < bb; ++j) off += s_counts[j];

  const int i = (sl << 8) + threadIdx.x;  // cell in [0, NCELL)
  const int w = i >> 5;
  const float* T = tokens + (size_t)bb * NCELL * NC;
  const float* C = T + (size_t)i * NC;
  float t0 = C[0], t1 = C[1], t2 = C[2], t3 = C[3], t4 = C[4], t5 = C[5],
        t6 = C[6], t7 = C[7], t8 = C[8];
  int packed = ((const int*)out)[((size_t)bb * NCELL + i) * 10 + 9];
  int mm = (int)(int8_t)(packed & 0xFF);
  int sc = (int)(int8_t)((packed >> 8) & 0xFF);
  int pc = (int)(int8_t)((packed >> 16) & 0xFF);

  float o0 = (mm >= 0) ? sqrtf(chainsums[bb * KK + mm]) : t0;
  float o3 = t3, o5 = t5, o7 = t7;
  if (pc >= 0) {  // predecessor at (w-1, pc) rewrites my start-side fields
    const float* P = T + (size_t)((w - 1) * KK + pc) * NC;
    float fep = P[4], aep = P[6], pep = P[8];
    o3 = (fep + t3) * 0.5f;
    o5 = (aep + t5) * 0.5f;
    float corr = wrapf(t7 - pep);
    o7 = t7 - corr * 0.5f;
  }
  float o4 = t4, o6 = t6, o8 = t8;
  if (sc >= 0) {  // successor at (w+1, sc) rewrites my end-side fields
    const float* S = T + (size_t)((w + 1) * KK + sc) * NC;
    float fsn = S[3], asn = S[5], psn = S[7];
    o4 = (t4 + fsn) * 0.5f;
    o6 = (t6 + asn) * 0.5f;
    float corr = wrapf(psn - t8);
    o8 = t8 + corr * 0.5f;
  }
  float* O = out + ((size_t)bb * NCELL + i) * 10;
  O[0] = o0; O[1] = t1; O[2] = t2; O[3] = o3; O[4] = o4;
  O[5] = o5; O[6] = o6; O[7] = o7; O[8] = o8;
  O[9] = (mm >= 0) ? (float)(mm + off) : -1.0f;
}

extern "C" void kernel_launch(void* const* d_in, const int* in_sizes, int n_in,
                              void* d_out, int out_size, void* d_ws,
                              size_t ws_size, hipStream_t stream) {
  const float* tokens = (const float*)d_in[0];
  float* out = (float*)d_out;
  int B = in_sizes[0] / (WW * KK * NC);
  int* counts = (int*)d_ws;                          // B ints
  float* chainsums = (float*)((char*)d_ws + 1024);   // B*KK floats
  dp_kernel<<<dim3(B), dim3(256), 0, stream>>>(tokens, out, counts, chainsums);
  out_kernel<<<dim3(B * OSLICES), dim3(256), 0, stream>>>(tokens, out, counts,
                                                          chainsums, B);
}